// Round 3
// baseline (1268.556 us; speedup 1.0000x reference)
//
#include <hip/hip_runtime.h>
#include <hip/hip_bf16.h>
#include <stdint.h>

#define NTOK 8192
#define DDIM 1024
#define HDIM 4096
#define NEXP 8

typedef __attribute__((ext_vector_type(4))) float f32x4;
typedef __attribute__((ext_vector_type(8))) short s16x8;
typedef __attribute__((ext_vector_type(8))) unsigned short u16x8;

__device__ __forceinline__ unsigned short f2bf(float f) {
  union { float f; unsigned int u; } v; v.f = f;
  unsigned int u = v.u;
  u += 0x7FFFu + ((u >> 16) & 1u);   // round-to-nearest-even
  return (unsigned short)(u >> 16);
}

typedef __attribute__((address_space(3))) unsigned char lds_u8;
typedef const __attribute__((address_space(1))) unsigned char glb_u8;

__device__ __forceinline__ void load_lds16(const void* g, void* l) {
  __builtin_amdgcn_global_load_lds((glb_u8*)g, (lds_u8*)l, 16, 0, 0);
}

// ---------------- gate + top-1 routing ----------------
__global__ __launch_bounds__(256) void gate_kernel(
    const float* __restrict__ x, const float* __restrict__ Wg,
    const float* __restrict__ bg, int* __restrict__ counts,
    int* __restrict__ lists) {
  const int lane = threadIdx.x & 63;
  const int tok = blockIdx.x * 4 + (threadIdx.x >> 6);
  const float* xr = x + (size_t)tok * DDIM;
  double acc[NEXP];
#pragma unroll
  for (int e = 0; e < NEXP; ++e) acc[e] = 0.0;
#pragma unroll 4
  for (int it = 0; it < DDIM / 64; ++it) {
    const int d = it * 64 + lane;
    const float xv = xr[d];
    const f32x4 w0 = *(const f32x4*)(Wg + (size_t)d * NEXP);
    const f32x4 w1 = *(const f32x4*)(Wg + (size_t)d * NEXP + 4);
#pragma unroll
    for (int j = 0; j < 4; ++j) {
      acc[j]     += (double)xv * (double)w0[j];
      acc[4 + j] += (double)xv * (double)w1[j];
    }
  }
#pragma unroll
  for (int e = 0; e < NEXP; ++e) {
    double v = acc[e];
#pragma unroll
    for (int off = 32; off > 0; off >>= 1) v += __shfl_xor(v, off, 64);
    acc[e] = v;
  }
  if (lane == 0) {
    int best = 0;
    double bv = acc[0] + (double)bg[0];
#pragma unroll
    for (int e = 1; e < NEXP; ++e) {
      const double v = acc[e] + (double)bg[e];
      if (v > bv) { bv = v; best = e; }   // strict > : first max wins (np argmax)
    }
    const int pos = atomicAdd(&counts[best], 1);
    lists[best * NTOK + pos] = tok;
  }
}

// ---------------- prefix sum of expert counts ----------------
__global__ void offs_kernel(const int* __restrict__ counts, int* __restrict__ offs) {
  int s = 0;
#pragma unroll
  for (int e = 0; e < NEXP; ++e) { offs[e] = s; s += counts[e]; }
  offs[NEXP] = s;
}

// -------- gather tokens into expert-sorted order, convert to bf16 --------
__global__ __launch_bounds__(256) void gather_conv_kernel(
    const float* __restrict__ x, const int* __restrict__ offs,
    const int* __restrict__ lists, int* __restrict__ stok,
    unsigned short* __restrict__ xbs) {
  const int p = blockIdx.x * 4 + (threadIdx.x >> 6);   // sorted position
  const int lane = threadIdx.x & 63;
  int e = 0;
#pragma unroll
  for (int k = 1; k < NEXP; ++k) e += (p >= offs[k]) ? 1 : 0;
  const int tok = lists[e * NTOK + (p - offs[e])];
  if (lane == 0) stok[p] = tok;
  const float* src = x + (size_t)tok * DDIM + lane * 16;
  unsigned short* dst = xbs + (size_t)p * DDIM + lane * 16;
#pragma unroll
  for (int q = 0; q < 2; ++q) {
    const f32x4 a = *(const f32x4*)(src + q * 8);
    const f32x4 b = *(const f32x4*)(src + q * 8 + 4);
    u16x8 o;
#pragma unroll
    for (int j = 0; j < 4; ++j) { o[j] = f2bf(a[j]); o[4 + j] = f2bf(b[j]); }
    *(u16x8*)(dst + q * 8) = o;
  }
}

// -------- transpose + convert: in [E][R][C] fp32 -> out [E][C][R] bf16 --------
__global__ __launch_bounds__(256) void transpose_conv_kernel(
    const float* __restrict__ in, unsigned short* __restrict__ out,
    int R, int C) {
  __shared__ unsigned short T[64][66];
  const int e = blockIdx.z;
  const float* ine = in + (size_t)e * R * C;
  unsigned short* oute = out + (size_t)e * C * R;
  const int c0 = blockIdx.x * 64, r0 = blockIdx.y * 64;
  const int t = threadIdx.x;
  const int tr = t >> 4, tc4 = (t & 15) * 4;
#pragma unroll
  for (int p = 0; p < 4; ++p) {
    const int r = tr + p * 16;
    const f32x4 v = *(const f32x4*)(ine + (size_t)(r0 + r) * C + c0 + tc4);
#pragma unroll
    for (int j = 0; j < 4; ++j) T[r][tc4 + j] = f2bf(v[j]);
  }
  __syncthreads();
#pragma unroll
  for (int p = 0; p < 4; ++p) {
    const int c = tr + p * 16;
    ushort4 o;
    o.x = T[tc4 + 0][c]; o.y = T[tc4 + 1][c];
    o.z = T[tc4 + 2][c]; o.w = T[tc4 + 3][c];
    *(ushort4*)(oute + (size_t)(c0 + c) * R + r0 + tc4) = o;
  }
}

// ---------------- grouped GEMM, 2-phase double-buffered, BK=64 ----------------
// A: bf16 [NTOK][K], rows in expert-sorted order. Bt: bf16 [E][N][K].
// FUSE1: outb[pos][col] = bf16 relu(acc+bias). else: outf[stok[pos]][col] = acc+bias.
// LDS XOR-swizzle: LDS col-block q of row r holds global col-block q^(r&7)
// (pre-swizzled global source, linear LDS dest for global_load_lds; swizzled ds_read).
template <int BM, int BN, int WVM, int WVN, int K, int N, bool FUSE1>
__global__ __launch_bounds__(64 * WVM * WVN, 2) void ffn_kernel(
    const unsigned short* __restrict__ A, const unsigned short* __restrict__ Bt,
    const float* __restrict__ bias, const int* __restrict__ counts,
    const int* __restrict__ offs, const int* __restrict__ stok,
    unsigned short* __restrict__ outb, float* __restrict__ outf) {
  constexpr int T = 64 * WVM * WVN;   // threads
  constexpr int RPI = T / 8;          // rows staged per global_load_lds issue (row=128B)
  constexpr int ISS_A = BM / RPI;
  constexpr int ISS_B = BN / RPI;
  constexpr int MF = BM / (WVM * 16);
  constexpr int NF = BN / (WVN * 16);
  constexpr int NT = K / 64;

  const int e = blockIdx.z;
  const int cnt = counts[e];
  const int bx = blockIdx.x;
  if (bx * BM >= cnt) return;
  const int row0 = offs[e] + bx * BM;
  const int col0 = blockIdx.y * BN;

  __shared__ __align__(16) unsigned short As[2][BM][64];
  __shared__ __align__(16) unsigned short Bs[2][BN][64];
  __shared__ int stok_blk[FUSE1 ? 1 : BM];

  const int tid = threadIdx.x;
  const int lane = tid & 63;
  const int w = tid >> 6;
  const int wm = w / WVN;
  const int wn = w % WVN;
  const int fr = lane & 15;
  const int fj = lane >> 4;

  if constexpr (!FUSE1) {
    if (tid < BM) {
      const int gr = row0 + tid;
      stok_blk[tid] = stok[gr < NTOK ? gr : NTOK - 1];
    }
  }

  // staging addresses: lane writes LDS col-block (tid&7) of row rb=i*RPI+(tid>>3);
  // source col-block pre-swizzled: (tid&7) ^ (row&7), row&7 == (tid>>3)&7.
  const int swz = (((tid & 7) ^ ((tid >> 3) & 7))) * 8;   // ushort offset in row
  const int rb = tid >> 3;
  const unsigned short* srcA[ISS_A];
#pragma unroll
  for (int i = 0; i < ISS_A; ++i) {
    int gr = row0 + i * RPI + rb;
    if (gr > NTOK - 1) gr = NTOK - 1;   // clamp: garbage only feeds invalid rows
    srcA[i] = A + (size_t)gr * K + swz;
  }
  const unsigned short* Bte = Bt + (size_t)e * N * K;
  const unsigned short* srcB[ISS_B];
#pragma unroll
  for (int i = 0; i < ISS_B; ++i)
    srcB[i] = Bte + (size_t)(col0 + i * RPI + rb) * K + swz;

  f32x4 acc[MF][NF];
#pragma unroll
  for (int m = 0; m < MF; ++m)
#pragma unroll
    for (int n = 0; n < NF; ++n) acc[m][n] = f32x4{0.f, 0.f, 0.f, 0.f};

  auto stage = [&](int buf, int k0) {
    unsigned short* dA = &As[buf][0][0];
    unsigned short* dB = &Bs[buf][0][0];
#pragma unroll
    for (int i = 0; i < ISS_A; ++i)
      load_lds16(srcA[i] + k0, dA + i * RPI * 64 + tid * 8);
#pragma unroll
    for (int i = 0; i < ISS_B; ++i)
      load_lds16(srcB[i] + k0, dB + i * RPI * 64 + tid * 8);
  };

  auto compute_tile = [&](int buf) {
    const unsigned short* pA = &As[buf][0][0];
    const unsigned short* pB = &Bs[buf][0][0];
#pragma unroll
    for (int kk = 0; kk < 2; ++kk) {
      const int js = (((kk << 2) + fj) ^ (fr & 7)) << 3;  // swizzled ushort offset
      s16x8 af[MF], bf[NF];
#pragma unroll
      for (int m = 0; m < MF; ++m)
        af[m] = *(const s16x8*)(pA + (wm * MF * 16 + m * 16 + fr) * 64 + js);
#pragma unroll
      for (int n = 0; n < NF; ++n)
        bf[n] = *(const s16x8*)(pB + (wn * NF * 16 + n * 16 + fr) * 64 + js);
#pragma unroll
      for (int m = 0; m < MF; ++m)
#pragma unroll
        for (int n = 0; n < NF; ++n)
          acc[m][n] = __builtin_amdgcn_mfma_f32_16x16x32_bf16(af[m], bf[n],
                                                              acc[m][n], 0, 0, 0);
    }
  };

  // prologue: stage tile 0
  stage(0, 0);
  __syncthreads();

  int cur = 0;
  for (int t = 0; t < NT - 1; ++t) {
    stage(cur ^ 1, (t + 1) * 64);   // issue next tile's loads FIRST (overlap)
    compute_tile(cur);
    __syncthreads();                 // drains vmcnt(0): next tile landed
    cur ^= 1;
  }
  compute_tile(cur);

  // epilogue
#pragma unroll
  for (int n = 0; n < NF; ++n) {
    const int col = col0 + wn * NF * 16 + n * 16 + fr;
    const float bv = bias[e * N + col];
#pragma unroll
    for (int m = 0; m < MF; ++m) {
#pragma unroll
      for (int j = 0; j < 4; ++j) {
        const int rl = wm * MF * 16 + m * 16 + fj * 4 + j;
        if (bx * BM + rl < cnt) {
          if constexpr (FUSE1) {
            outb[(size_t)(row0 + rl) * N + col] = f2bf(fmaxf(acc[m][n][j] + bv, 0.f));
          } else {
            outf[(size_t)stok_blk[rl] * N + col] = acc[m][n][j] + bv;
          }
        }
      }
    }
  }
}

extern "C" void kernel_launch(void* const* d_in, const int* in_sizes, int n_in,
                              void* d_out, int out_size, void* d_ws, size_t ws_size,
                              hipStream_t stream) {
  (void)in_sizes; (void)n_in; (void)out_size;
  const float* x  = (const float*)d_in[0];
  const float* Wg = (const float*)d_in[1];
  const float* bg = (const float*)d_in[2];
  const float* W1 = (const float*)d_in[3];
  const float* b1 = (const float*)d_in[4];
  const float* W2 = (const float*)d_in[5];
  const float* b2 = (const float*)d_in[6];
  float* out = (float*)d_out;

  char* ws = (char*)d_ws;
  const size_t OFF_CNT = 0;                                    // 8 ints
  const size_t OFF_OFF = 128;                                  // 9 ints
  const size_t OFF_LST = 256;                                  // E*NTOK ints (256 KB)
  const size_t OFF_STK = OFF_LST + (size_t)NEXP * NTOK * 4;    // NTOK ints (32 KB)
  const size_t OFF_XBS = OFF_STK + (size_t)NTOK * 4;           // NTOK*D bf16 (16 MB)
  const size_t OFF_HS  = OFF_XBS + (size_t)NTOK * DDIM * 2;    // NTOK*H bf16 (64 MB)
  const size_t OFF_WT  = OFF_HS + (size_t)NTOK * HDIM * 2;     // E*D*H bf16 (64 MB)
  const size_t NEED    = OFF_WT + (size_t)NEXP * DDIM * HDIM * 2;
  if (ws_size < NEED) return;

  int* counts = (int*)(ws + OFF_CNT);
  int* offs   = (int*)(ws + OFF_OFF);
  int* lists  = (int*)(ws + OFF_LST);
  int* stok   = (int*)(ws + OFF_STK);
  unsigned short* xbs = (unsigned short*)(ws + OFF_XBS);
  unsigned short* Hs  = (unsigned short*)(ws + OFF_HS);
  unsigned short* Wt  = (unsigned short*)(ws + OFF_WT);

  hipMemsetAsync(counts, 0, 128, stream);
  gate_kernel<<<NTOK / 4, 256, 0, stream>>>(x, Wg, bg, counts, lists);
  offs_kernel<<<1, 1, 0, stream>>>(counts, offs);
  gather_conv_kernel<<<NTOK / 4, 256, 0, stream>>>(x, offs, lists, stok, xbs);

  // W1 [E][D][H] -> Wt [E][H][D]
  transpose_conv_kernel<<<dim3(HDIM / 64, DDIM / 64, NEXP), 256, 0, stream>>>(
      W1, Wt, DDIM, HDIM);
  // ffn1: Hs[pos] = relu(xbs[pos] @ W1[e] + b1[e]) ; 256x256, 8 waves
  ffn_kernel<256, 256, 2, 4, DDIM, HDIM, true>
      <<<dim3(NTOK / 256, HDIM / 256, NEXP), 512, 0, stream>>>(
          xbs, Wt, b1, counts, offs, stok, Hs, nullptr);
  // W2 [E][H][D] -> Wt [E][D][H]  (reuse buffer after ffn1)
  transpose_conv_kernel<<<dim3(DDIM / 64, HDIM / 64, NEXP), 256, 0, stream>>>(
      W2, Wt, HDIM, DDIM);
  // ffn2: out[stok[pos]] = Hs[pos] @ W2[e] + b2[e] ; 128x128, 4 waves
  ffn_kernel<128, 128, 2, 2, HDIM, DDIM, false>
      <<<dim3(NTOK / 128, DDIM / 128, NEXP), 256, 0, stream>>>(
          Hs, Wt, b2, counts, offs, stok, nullptr, out);
}

// Round 4
// 1197.661 us; speedup vs baseline: 1.0592x; 1.0592x over previous
//
#include <hip/hip_runtime.h>
#include <hip/hip_bf16.h>
#include <stdint.h>

#define NTOK 8192
#define DDIM 1024
#define HDIM 4096
#define NEXP 8

typedef __attribute__((ext_vector_type(4))) float f32x4;
typedef __attribute__((ext_vector_type(8))) short s16x8;
typedef __attribute__((ext_vector_type(8))) unsigned short u16x8;

__device__ __forceinline__ unsigned short f2bf(float f) {
  union { float f; unsigned int u; } v; v.f = f;
  unsigned int u = v.u;
  u += 0x7FFFu + ((u >> 16) & 1u);   // round-to-nearest-even
  return (unsigned short)(u >> 16);
}

typedef __attribute__((address_space(3))) unsigned char lds_u8;
typedef const __attribute__((address_space(1))) unsigned char glb_u8;

__device__ __forceinline__ void load_lds16(const void* g, void* l) {
  __builtin_amdgcn_global_load_lds((glb_u8*)g, (lds_u8*)l, 16, 0, 0);
}

// ---------------- gate + top-1 routing ----------------
__global__ __launch_bounds__(256) void gate_kernel(
    const float* __restrict__ x, const float* __restrict__ Wg,
    const float* __restrict__ bg, int* __restrict__ counts,
    int* __restrict__ lists) {
  const int lane = threadIdx.x & 63;
  const int tok = blockIdx.x * 4 + (threadIdx.x >> 6);
  const float* xr = x + (size_t)tok * DDIM;
  double acc[NEXP];
#pragma unroll
  for (int e = 0; e < NEXP; ++e) acc[e] = 0.0;
#pragma unroll 4
  for (int it = 0; it < DDIM / 64; ++it) {
    const int d = it * 64 + lane;
    const float xv = xr[d];
    const f32x4 w0 = *(const f32x4*)(Wg + (size_t)d * NEXP);
    const f32x4 w1 = *(const f32x4*)(Wg + (size_t)d * NEXP + 4);
#pragma unroll
    for (int j = 0; j < 4; ++j) {
      acc[j]     += (double)xv * (double)w0[j];
      acc[4 + j] += (double)xv * (double)w1[j];
    }
  }
#pragma unroll
  for (int e = 0; e < NEXP; ++e) {
    double v = acc[e];
#pragma unroll
    for (int off = 32; off > 0; off >>= 1) v += __shfl_xor(v, off, 64);
    acc[e] = v;
  }
  if (lane == 0) {
    int best = 0;
    double bv = acc[0] + (double)bg[0];
#pragma unroll
    for (int e = 1; e < NEXP; ++e) {
      const double v = acc[e] + (double)bg[e];
      if (v > bv) { bv = v; best = e; }   // strict > : first max wins (np argmax)
    }
    const int pos = atomicAdd(&counts[best], 1);
    lists[best * NTOK + pos] = tok;
  }
}

// ---------------- prefix sum of expert counts ----------------
__global__ void offs_kernel(const int* __restrict__ counts, int* __restrict__ offs) {
  int s = 0;
#pragma unroll
  for (int e = 0; e < NEXP; ++e) { offs[e] = s; s += counts[e]; }
  offs[NEXP] = s;
}

// -------- gather tokens into expert-sorted order, convert to bf16 --------
__global__ __launch_bounds__(256) void gather_conv_kernel(
    const float* __restrict__ x, const int* __restrict__ offs,
    const int* __restrict__ lists, int* __restrict__ stok,
    unsigned short* __restrict__ xbs) {
  const int p = blockIdx.x * 4 + (threadIdx.x >> 6);   // sorted position
  const int lane = threadIdx.x & 63;
  int e = 0;
#pragma unroll
  for (int k = 1; k < NEXP; ++k) e += (p >= offs[k]) ? 1 : 0;
  const int tok = lists[e * NTOK + (p - offs[e])];
  if (lane == 0) stok[p] = tok;
  const float* src = x + (size_t)tok * DDIM + lane * 16;
  unsigned short* dst = xbs + (size_t)p * DDIM + lane * 16;
#pragma unroll
  for (int q = 0; q < 2; ++q) {
    const f32x4 a = *(const f32x4*)(src + q * 8);
    const f32x4 b = *(const f32x4*)(src + q * 8 + 4);
    u16x8 o;
#pragma unroll
    for (int j = 0; j < 4; ++j) { o[j] = f2bf(a[j]); o[4 + j] = f2bf(b[j]); }
    *(u16x8*)(dst + q * 8) = o;
  }
}

// -------- transpose + convert: in [E][R][C] fp32 -> out [E][C][R] bf16 --------
__global__ __launch_bounds__(256) void transpose_conv_kernel(
    const float* __restrict__ in, unsigned short* __restrict__ out,
    int R, int C) {
  __shared__ unsigned short T[64][66];
  const int e = blockIdx.z;
  const float* ine = in + (size_t)e * R * C;
  unsigned short* oute = out + (size_t)e * C * R;
  const int c0 = blockIdx.x * 64, r0 = blockIdx.y * 64;
  const int t = threadIdx.x;
  const int tr = t >> 4, tc4 = (t & 15) * 4;
#pragma unroll
  for (int p = 0; p < 4; ++p) {
    const int r = tr + p * 16;
    const f32x4 v = *(const f32x4*)(ine + (size_t)(r0 + r) * C + c0 + tc4);
#pragma unroll
    for (int j = 0; j < 4; ++j) T[r][tc4 + j] = f2bf(v[j]);
  }
  __syncthreads();
#pragma unroll
  for (int p = 0; p < 4; ++p) {
    const int c = tr + p * 16;
    ushort4 o;
    o.x = T[tc4 + 0][c]; o.y = T[tc4 + 1][c];
    o.z = T[tc4 + 2][c]; o.w = T[tc4 + 3][c];
    *(ushort4*)(oute + (size_t)(c0 + c) * R + r0 + tc4) = o;
  }
}

// ------- grouped GEMM, 2-phase dbuf with raw barriers + explicit waitcnt -------
// A: bf16 [NTOK][K], rows expert-sorted. Bt: bf16 [E][N][K] (K-contiguous rows).
// Phase discipline (m201-style, plain HIP):
//   vmcnt(0); s_barrier;            // current tile landed (only its loads outstanding)
//   ds_read current -> regs;        // reads issued BEFORE next stage (no alias hazard)
//   stage(next tile);               // 8 global_load_lds, in flight under MFMA
//   MFMA;                           // compiler inserts lgkm waits
// LDS XOR-swizzle: LDS[row][cb] holds global col-block cb^(row&7) (16B blocks);
// linear LDS dest for global_load_lds + pre-swizzled global src + swizzled ds_read.
template <int BM, int BN, int WVM, int WVN, int K, int N, bool FUSE1>
__global__ __launch_bounds__(64 * WVM * WVN, 2) void ffn_kernel(
    const unsigned short* __restrict__ A, const unsigned short* __restrict__ Bt,
    const float* __restrict__ bias, const int* __restrict__ counts,
    const int* __restrict__ offs, const int* __restrict__ stok,
    unsigned short* __restrict__ outb, float* __restrict__ outf) {
  constexpr int T = 64 * WVM * WVN;
  constexpr int RPI = T / 8;          // rows per staging issue (row = 128 B)
  constexpr int ISS_A = BM / RPI;
  constexpr int ISS_B = BN / RPI;
  constexpr int MF = BM / (WVM * 16);
  constexpr int NF = BN / (WVN * 16);
  constexpr int NT = K / 64;
  static_assert(NT >= 4 && (NT & 1) == 0, "NT even");

  const int e = blockIdx.z;
  const int cnt = counts[e];
  const int bx = blockIdx.x;
  if (bx * BM >= cnt) return;
  const int row0 = offs[e] + bx * BM;
  const int col0 = blockIdx.y * BN;

  __shared__ __align__(16) unsigned short As0[BM][64];
  __shared__ __align__(16) unsigned short Bs0[BN][64];
  __shared__ __align__(16) unsigned short As1[BM][64];
  __shared__ __align__(16) unsigned short Bs1[BN][64];

  const int tid = threadIdx.x;
  const int lane = tid & 63;
  const int w = tid >> 6;
  const int wm = w / WVN;
  const int wn = w % WVN;
  const int fr = lane & 15;
  const int fj = lane >> 4;

  // staging: thread stages LDS row rb = i*RPI + (tid>>3), col-block (tid&7);
  // global source col-block pre-swizzled by ^(row&7).
  const int swz = ((tid & 7) ^ ((tid >> 3) & 7)) * 8;   // ushort offset
  const int rb = tid >> 3;
  const unsigned short* srcA[ISS_A];
#pragma unroll
  for (int i = 0; i < ISS_A; ++i) {
    int gr = row0 + i * RPI + rb;
    if (gr > NTOK - 1) gr = NTOK - 1;   // clamp: garbage rows masked in epilogue
    srcA[i] = A + (size_t)gr * K + swz;
  }
  const unsigned short* Bte = Bt + (size_t)e * N * K;
  const unsigned short* srcB[ISS_B];
#pragma unroll
  for (int i = 0; i < ISS_B; ++i)
    srcB[i] = Bte + (size_t)(col0 + i * RPI + rb) * K + swz;

  f32x4 acc[MF][NF];
#pragma unroll
  for (int m = 0; m < MF; ++m)
#pragma unroll
    for (int n = 0; n < NF; ++n) acc[m][n] = f32x4{0.f, 0.f, 0.f, 0.f};

  auto stage = [&](unsigned short* dA, unsigned short* dB, int k0) {
#pragma unroll
    for (int i = 0; i < ISS_A; ++i)
      load_lds16(srcA[i] + k0, dA + i * RPI * 64 + tid * 8);
#pragma unroll
    for (int i = 0; i < ISS_B; ++i)
      load_lds16(srcB[i] + k0, dB + i * RPI * 64 + tid * 8);
  };

  // One K-tile phase. Reads current buffers, optionally stages next tile.
  auto phase = [&](const unsigned short* pA, const unsigned short* pB,
                   unsigned short* nA, unsigned short* nB, int knext,
                   bool do_stage) {
    asm volatile("s_waitcnt vmcnt(0)" ::: "memory");  // only current tile's loads outstanding
    __builtin_amdgcn_s_barrier();                     // all waves: tile landed, old reads done
    asm volatile("" ::: "memory");                    // keep ds_reads below the barrier
#pragma unroll
    for (int kk = 0; kk < 2; ++kk) {
      const int js = (((kk << 2) + fj) ^ (fr & 7)) << 3;  // swizzled ushort offset
      s16x8 af[MF], bf[NF];
#pragma unroll
      for (int m = 0; m < MF; ++m)
        af[m] = *(const s16x8*)(pA + (wm * MF * 16 + m * 16 + fr) * 64 + js);
#pragma unroll
      for (int n = 0; n < NF; ++n)
        bf[n] = *(const s16x8*)(pB + (wn * NF * 16 + n * 16 + fr) * 64 + js);
      if (kk == 0 && do_stage) stage(nA, nB, knext);   // issue next tile under MFMA
#pragma unroll
      for (int m = 0; m < MF; ++m)
#pragma unroll
        for (int n = 0; n < NF; ++n)
          acc[m][n] = __builtin_amdgcn_mfma_f32_16x16x32_bf16(af[m], bf[n],
                                                              acc[m][n], 0, 0, 0);
    }
  };

  unsigned short* A0 = &As0[0][0];
  unsigned short* B0 = &Bs0[0][0];
  unsigned short* A1 = &As1[0][0];
  unsigned short* B1 = &Bs1[0][0];

  stage(A0, B0, 0);   // prologue
#pragma unroll 1
  for (int t = 0; t < NT - 2; t += 2) {
    phase(A0, B0, A1, B1, (t + 1) * 64, true);
    phase(A1, B1, A0, B0, (t + 2) * 64, true);
  }
  phase(A0, B0, A1, B1, (NT - 1) * 64, true);
  phase(A1, B1, A0, B0, 0, false);

  // epilogue
#pragma unroll
  for (int n = 0; n < NF; ++n) {
    const int col = col0 + wn * NF * 16 + n * 16 + fr;
    const float bv = bias[e * N + col];
#pragma unroll
    for (int m = 0; m < MF; ++m) {
#pragma unroll
      for (int j = 0; j < 4; ++j) {
        const int rl = wm * MF * 16 + m * 16 + fj * 4 + j;
        if (bx * BM + rl < cnt) {
          if constexpr (FUSE1) {
            outb[(size_t)(row0 + rl) * N + col] = f2bf(fmaxf(acc[m][n][j] + bv, 0.f));
          } else {
            outf[(size_t)stok[row0 + rl] * N + col] = acc[m][n][j] + bv;
          }
        }
      }
    }
  }
}

extern "C" void kernel_launch(void* const* d_in, const int* in_sizes, int n_in,
                              void* d_out, int out_size, void* d_ws, size_t ws_size,
                              hipStream_t stream) {
  (void)in_sizes; (void)n_in; (void)out_size;
  const float* x  = (const float*)d_in[0];
  const float* Wg = (const float*)d_in[1];
  const float* bg = (const float*)d_in[2];
  const float* W1 = (const float*)d_in[3];
  const float* b1 = (const float*)d_in[4];
  const float* W2 = (const float*)d_in[5];
  const float* b2 = (const float*)d_in[6];
  float* out = (float*)d_out;

  char* ws = (char*)d_ws;
  const size_t OFF_CNT = 0;                                    // 8 ints
  const size_t OFF_OFF = 128;                                  // 9 ints
  const size_t OFF_LST = 256;                                  // E*NTOK ints (256 KB)
  const size_t OFF_STK = OFF_LST + (size_t)NEXP * NTOK * 4;    // NTOK ints (32 KB)
  const size_t OFF_XBS = OFF_STK + (size_t)NTOK * 4;           // NTOK*D bf16 (16 MB)
  const size_t OFF_HS  = OFF_XBS + (size_t)NTOK * DDIM * 2;    // NTOK*H bf16 (64 MB)
  const size_t OFF_WT  = OFF_HS + (size_t)NTOK * HDIM * 2;     // E*D*H bf16 (64 MB)
  const size_t NEED    = OFF_WT + (size_t)NEXP * DDIM * HDIM * 2;
  if (ws_size < NEED) return;

  int* counts = (int*)(ws + OFF_CNT);
  int* offs   = (int*)(ws + OFF_OFF);
  int* lists  = (int*)(ws + OFF_LST);
  int* stok   = (int*)(ws + OFF_STK);
  unsigned short* xbs = (unsigned short*)(ws + OFF_XBS);
  unsigned short* Hs  = (unsigned short*)(ws + OFF_HS);
  unsigned short* Wt  = (unsigned short*)(ws + OFF_WT);

  hipMemsetAsync(counts, 0, 128, stream);
  gate_kernel<<<NTOK / 4, 256, 0, stream>>>(x, Wg, bg, counts, lists);
  offs_kernel<<<1, 1, 0, stream>>>(counts, offs);
  gather_conv_kernel<<<NTOK / 4, 256, 0, stream>>>(x, offs, lists, stok, xbs);

  // W1 [E][D][H] -> Wt [E][H][D]
  transpose_conv_kernel<<<dim3(HDIM / 64, DDIM / 64, NEXP), 256, 0, stream>>>(
      W1, Wt, DDIM, HDIM);
  // ffn1: Hs[pos] = relu(xbs[pos] @ W1[e] + b1[e]) ; 256x256 tile, 8 waves
  ffn_kernel<256, 256, 2, 4, DDIM, HDIM, true>
      <<<dim3(NTOK / 256, HDIM / 256, NEXP), 512, 0, stream>>>(
          xbs, Wt, b1, counts, offs, stok, Hs, nullptr);
  // W2 [E][H][D] -> Wt [E][D][H]  (reuse buffer after ffn1)
  transpose_conv_kernel<<<dim3(DDIM / 64, HDIM / 64, NEXP), 256, 0, stream>>>(
      W2, Wt, HDIM, DDIM);
  // ffn2: out[stok[pos]] = Hs[pos] @ W2[e] + b2[e] ; 128x128 tile, 4 waves, 2 blk/CU
  ffn_kernel<128, 128, 2, 2, HDIM, DDIM, false>
      <<<dim3(NTOK / 128, DDIM / 128, NEXP), 256, 0, stream>>>(
          Hs, Wt, b2, counts, offs, stok, nullptr, out);
}

// Round 5
// 502.444 us; speedup vs baseline: 2.5248x; 2.3837x over previous
//
#include <hip/hip_runtime.h>
#include <hip/hip_bf16.h>
#include <stdint.h>

#define NTOK 8192
#define DDIM 1024
#define HDIM 4096
#define NEXP 8
#define MAXWL 72

typedef __attribute__((ext_vector_type(4))) float f32x4;
typedef __attribute__((ext_vector_type(8))) short s16x8;
typedef __attribute__((ext_vector_type(8))) unsigned short u16x8;

__device__ __forceinline__ unsigned short f2bf(float f) {
  union { float f; unsigned int u; } v; v.f = f;
  unsigned int u = v.u;
  u += 0x7FFFu + ((u >> 16) & 1u);   // round-to-nearest-even
  return (unsigned short)(u >> 16);
}

typedef __attribute__((address_space(3))) unsigned char lds_u8;
typedef const __attribute__((address_space(1))) unsigned char glb_u8;

__device__ __forceinline__ void load_lds16(const void* g, void* l) {
  __builtin_amdgcn_global_load_lds((glb_u8*)g, (lds_u8*)l, 16, 0, 0);
}

// ---------------- gate + top-1 routing ----------------
__global__ __launch_bounds__(256) void gate_kernel(
    const float* __restrict__ x, const float* __restrict__ Wg,
    const float* __restrict__ bg, int* __restrict__ counts,
    int* __restrict__ lists) {
  const int lane = threadIdx.x & 63;
  const int tok = blockIdx.x * 4 + (threadIdx.x >> 6);
  const float* xr = x + (size_t)tok * DDIM;
  double acc[NEXP];
#pragma unroll
  for (int e = 0; e < NEXP; ++e) acc[e] = 0.0;
#pragma unroll 4
  for (int it = 0; it < DDIM / 64; ++it) {
    const int d = it * 64 + lane;
    const float xv = xr[d];
    const f32x4 w0 = *(const f32x4*)(Wg + (size_t)d * NEXP);
    const f32x4 w1 = *(const f32x4*)(Wg + (size_t)d * NEXP + 4);
#pragma unroll
    for (int j = 0; j < 4; ++j) {
      acc[j]     += (double)xv * (double)w0[j];
      acc[4 + j] += (double)xv * (double)w1[j];
    }
  }
#pragma unroll
  for (int e = 0; e < NEXP; ++e) {
    double v = acc[e];
#pragma unroll
    for (int off = 32; off > 0; off >>= 1) v += __shfl_xor(v, off, 64);
    acc[e] = v;
  }
  if (lane == 0) {
    int best = 0;
    double bv = acc[0] + (double)bg[0];
#pragma unroll
    for (int e = 1; e < NEXP; ++e) {
      const double v = acc[e] + (double)bg[e];
      if (v > bv) { bv = v; best = e; }   // strict > : first max wins (np argmax)
    }
    const int pos = atomicAdd(&counts[best], 1);
    lists[best * NTOK + pos] = tok;
  }
}

// -------- prefix sum + block work-list: wl[i] = (e<<20)|bx, nwl in offs[9] --------
__global__ void offs_kernel(const int* __restrict__ counts, int* __restrict__ offs,
                            int* __restrict__ wl) {
  int s = 0;
#pragma unroll
  for (int e = 0; e < NEXP; ++e) { offs[e] = s; s += counts[e]; }
  offs[NEXP] = s;
  int n = 0;
  for (int e = 0; e < NEXP; ++e) {
    const int nb = (counts[e] + 127) >> 7;   // ceil(cnt/128)
    for (int b = 0; b < nb; ++b) wl[n++] = (e << 20) | b;
  }
  offs[NEXP + 1] = n;
}

// -------- gather tokens into expert-sorted order, convert to bf16 --------
__global__ __launch_bounds__(256) void gather_conv_kernel(
    const float* __restrict__ x, const int* __restrict__ offs,
    const int* __restrict__ lists, int* __restrict__ stok,
    unsigned short* __restrict__ xbs) {
  const int p = blockIdx.x * 4 + (threadIdx.x >> 6);   // sorted position
  const int lane = threadIdx.x & 63;
  int e = 0;
#pragma unroll
  for (int k = 1; k < NEXP; ++k) e += (p >= offs[k]) ? 1 : 0;
  const int tok = lists[e * NTOK + (p - offs[e])];
  if (lane == 0) stok[p] = tok;
  const float* src = x + (size_t)tok * DDIM + lane * 16;
  unsigned short* dst = xbs + (size_t)p * DDIM + lane * 16;
#pragma unroll
  for (int q = 0; q < 2; ++q) {
    const f32x4 a = *(const f32x4*)(src + q * 8);
    const f32x4 b = *(const f32x4*)(src + q * 8 + 4);
    u16x8 o;
#pragma unroll
    for (int j = 0; j < 4; ++j) { o[j] = f2bf(a[j]); o[4 + j] = f2bf(b[j]); }
    *(u16x8*)(dst + q * 8) = o;
  }
}

// -------- transpose + convert: in [E][R][C] fp32 -> out [E][C][R] bf16 --------
__global__ __launch_bounds__(256) void transpose_conv_kernel(
    const float* __restrict__ in, unsigned short* __restrict__ out,
    int R, int C) {
  __shared__ unsigned short T[64][66];
  const int e = blockIdx.z;
  const float* ine = in + (size_t)e * R * C;
  unsigned short* oute = out + (size_t)e * C * R;
  const int c0 = blockIdx.x * 64, r0 = blockIdx.y * 64;
  const int t = threadIdx.x;
  const int tr = t >> 4, tc4 = (t & 15) * 4;
#pragma unroll
  for (int p = 0; p < 4; ++p) {
    const int r = tr + p * 16;
    const f32x4 v = *(const f32x4*)(ine + (size_t)(r0 + r) * C + c0 + tc4);
#pragma unroll
    for (int j = 0; j < 4; ++j) T[r][tc4 + j] = f2bf(v[j]);
  }
  __syncthreads();
#pragma unroll
  for (int p = 0; p < 4; ++p) {
    const int c = tr + p * 16;
    ushort4 o;
    o.x = T[tc4 + 0][c]; o.y = T[tc4 + 1][c];
    o.z = T[tc4 + 2][c]; o.w = T[tc4 + 3][c];
    *(ushort4*)(oute + (size_t)(c0 + c) * R + r0 + tc4) = o;
  }
}

// ---- grouped GEMM: 128x128 tile, BK=64, 4 waves, 2 blocks/CU, 2-phase dbuf ----
// A: bf16 [NTOK][K] expert-sorted rows. Bt: bf16 [E][N][K] (K-contiguous rows).
// Work-list grid: blockIdx.x = column block, blockIdx.y = work-list index.
// Phase: vmcnt(0)+barrier -> ds_read WHOLE tile to regs -> stage next (in flight
// under MFMA) -> setprio(1)+MFMA. LDS XOR-swizzle (16B blocks) for conflict-free
// ds_read_b128; linear LDS dest (global_load_lds) + pre-swizzled global source.
template <int K, int N, bool FUSE1>
__global__ __launch_bounds__(256, 2) void ffn_kernel(
    const unsigned short* __restrict__ A, const unsigned short* __restrict__ Bt,
    const float* __restrict__ bias, const int* __restrict__ counts,
    const int* __restrict__ offs, const int* __restrict__ wl,
    const int* __restrict__ stok, unsigned short* __restrict__ outb,
    float* __restrict__ outf) {
  constexpr int BM = 128, BN = 128;
  constexpr int MF = 4, NF = 4;       // 2x2 waves, 64x64 per wave
  constexpr int NT = K / 64;
  static_assert((NT & 1) == 0 && NT >= 4, "");

  if ((int)blockIdx.y >= offs[NEXP + 1]) return;
  const int wle = wl[blockIdx.y];
  const int e = wle >> 20;
  const int bx = wle & 0xFFFFF;
  const int cnt = counts[e];
  const int row0 = offs[e] + bx * BM;
  const int col0 = blockIdx.x * BN;

  __shared__ __align__(16) unsigned short As0[BM][64];
  __shared__ __align__(16) unsigned short Bs0[BN][64];
  __shared__ __align__(16) unsigned short As1[BM][64];
  __shared__ __align__(16) unsigned short Bs1[BN][64];

  const int tid = threadIdx.x;
  const int lane = tid & 63;
  const int w = tid >> 6;
  const int wm = w >> 1;
  const int wn = w & 1;
  const int fr = lane & 15;
  const int fj = lane >> 4;

  // staging: thread -> LDS row rb = i*32 + (tid>>3), col-block (tid&7);
  // global source col-block pre-swizzled by ^(row&7).
  const int swz = ((tid & 7) ^ ((tid >> 3) & 7)) * 8;   // ushort offset
  const int rb = tid >> 3;
  const unsigned short* srcA[4];
#pragma unroll
  for (int i = 0; i < 4; ++i) {
    int gr = row0 + i * 32 + rb;
    if (gr > NTOK - 1) gr = NTOK - 1;   // clamp: garbage rows masked in epilogue
    srcA[i] = A + (size_t)gr * K + swz;
  }
  const unsigned short* Bte = Bt + (size_t)e * N * K;
  const unsigned short* srcB[4];
#pragma unroll
  for (int i = 0; i < 4; ++i)
    srcB[i] = Bte + (size_t)(col0 + i * 32 + rb) * K + swz;

  f32x4 acc[MF][NF];
#pragma unroll
  for (int m = 0; m < MF; ++m)
#pragma unroll
    for (int n = 0; n < NF; ++n) acc[m][n] = f32x4{0.f, 0.f, 0.f, 0.f};

  auto stage = [&](unsigned short* dA, unsigned short* dB, int k0) {
#pragma unroll
    for (int i = 0; i < 4; ++i)
      load_lds16(srcA[i] + k0, dA + i * 32 * 64 + tid * 8);
#pragma unroll
    for (int i = 0; i < 4; ++i)
      load_lds16(srcB[i] + k0, dB + i * 32 * 64 + tid * 8);
  };

  auto phase = [&](const unsigned short* pA, const unsigned short* pB,
                   unsigned short* nA, unsigned short* nB, int knext,
                   bool do_stage) {
    asm volatile("s_waitcnt vmcnt(0)" ::: "memory");  // current tile landed
    __builtin_amdgcn_s_barrier();
    // read the WHOLE tile into registers BEFORE issuing next stage (no alias waits)
    s16x8 af[2][MF], bf[2][NF];
#pragma unroll
    for (int kk = 0; kk < 2; ++kk) {
      const int js = (((kk << 2) + fj) ^ (fr & 7)) << 3;  // swizzled ushort offset
#pragma unroll
      for (int m = 0; m < MF; ++m)
        af[kk][m] = *(const s16x8*)(pA + (wm * 64 + m * 16 + fr) * 64 + js);
#pragma unroll
      for (int n = 0; n < NF; ++n)
        bf[kk][n] = *(const s16x8*)(pB + (wn * 64 + n * 16 + fr) * 64 + js);
    }
    if (do_stage) stage(nA, nB, knext);   // 8 global_load_lds, fly under MFMA
    __builtin_amdgcn_s_setprio(1);
#pragma unroll
    for (int kk = 0; kk < 2; ++kk)
#pragma unroll
      for (int m = 0; m < MF; ++m)
#pragma unroll
        for (int n = 0; n < NF; ++n)
          acc[m][n] = __builtin_amdgcn_mfma_f32_16x16x32_bf16(
              af[kk][m], bf[kk][n], acc[m][n], 0, 0, 0);
    __builtin_amdgcn_s_setprio(0);
  };

  unsigned short* A0 = &As0[0][0];
  unsigned short* B0 = &Bs0[0][0];
  unsigned short* A1 = &As1[0][0];
  unsigned short* B1 = &Bs1[0][0];

  stage(A0, B0, 0);   // prologue
#pragma unroll 1
  for (int t = 0; t + 2 < NT; t += 2) {
    phase(A0, B0, A1, B1, (t + 1) * 64, true);
    phase(A1, B1, A0, B0, (t + 2) * 64, true);
  }
  phase(A0, B0, A1, B1, (NT - 1) * 64, true);
  phase(A1, B1, A0, B0, 0, false);

  // epilogue
#pragma unroll
  for (int n = 0; n < NF; ++n) {
    const int col = col0 + wn * 64 + n * 16 + fr;
    const float bv = bias[e * N + col];
#pragma unroll
    for (int m = 0; m < MF; ++m) {
#pragma unroll
      for (int j = 0; j < 4; ++j) {
        const int rl = wm * 64 + m * 16 + fj * 4 + j;
        if (bx * BM + rl < cnt) {
          if constexpr (FUSE1) {
            outb[(size_t)(row0 + rl) * N + col] = f2bf(fmaxf(acc[m][n][j] + bv, 0.f));
          } else {
            outf[(size_t)stok[row0 + rl] * N + col] = acc[m][n][j] + bv;
          }
        }
      }
    }
  }
}

extern "C" void kernel_launch(void* const* d_in, const int* in_sizes, int n_in,
                              void* d_out, int out_size, void* d_ws, size_t ws_size,
                              hipStream_t stream) {
  (void)in_sizes; (void)n_in; (void)out_size;
  const float* x  = (const float*)d_in[0];
  const float* Wg = (const float*)d_in[1];
  const float* bg = (const float*)d_in[2];
  const float* W1 = (const float*)d_in[3];
  const float* b1 = (const float*)d_in[4];
  const float* W2 = (const float*)d_in[5];
  const float* b2 = (const float*)d_in[6];
  float* out = (float*)d_out;

  char* ws = (char*)d_ws;
  const size_t OFF_CNT = 0;                                    // 8 ints
  const size_t OFF_OFF = 128;                                  // 16 ints (offs + nwl)
  const size_t OFF_WL  = 256;                                  // MAXWL ints
  const size_t OFF_LST = 1024;                                 // E*NTOK ints (256 KB)
  const size_t OFF_STK = OFF_LST + (size_t)NEXP * NTOK * 4;    // NTOK ints
  const size_t OFF_XBS = OFF_STK + (size_t)NTOK * 4;           // NTOK*D bf16 (16 MB)
  const size_t OFF_HS  = OFF_XBS + (size_t)NTOK * DDIM * 2;    // NTOK*H bf16 (64 MB)
  const size_t OFF_WT  = OFF_HS + (size_t)NTOK * HDIM * 2;     // E*D*H bf16 (64 MB)
  const size_t NEED    = OFF_WT + (size_t)NEXP * DDIM * HDIM * 2;
  if (ws_size < NEED) return;

  int* counts = (int*)(ws + OFF_CNT);
  int* offs   = (int*)(ws + OFF_OFF);
  int* wl     = (int*)(ws + OFF_WL);
  int* lists  = (int*)(ws + OFF_LST);
  int* stok   = (int*)(ws + OFF_STK);
  unsigned short* xbs = (unsigned short*)(ws + OFF_XBS);
  unsigned short* Hs  = (unsigned short*)(ws + OFF_HS);
  unsigned short* Wt  = (unsigned short*)(ws + OFF_WT);

  hipMemsetAsync(counts, 0, 128, stream);
  gate_kernel<<<NTOK / 4, 256, 0, stream>>>(x, Wg, bg, counts, lists);
  offs_kernel<<<1, 1, 0, stream>>>(counts, offs, wl);
  gather_conv_kernel<<<NTOK / 4, 256, 0, stream>>>(x, offs, lists, stok, xbs);

  // W1 [E][D][H] -> Wt [E][H][D]
  transpose_conv_kernel<<<dim3(HDIM / 64, DDIM / 64, NEXP), 256, 0, stream>>>(
      W1, Wt, DDIM, HDIM);
  // ffn1: Hs[pos] = relu(xbs[pos] @ W1[e] + b1[e])
  ffn_kernel<DDIM, HDIM, true>
      <<<dim3(HDIM / 128, MAXWL), 256, 0, stream>>>(
          xbs, Wt, b1, counts, offs, wl, stok, Hs, nullptr);
  // W2 [E][H][D] -> Wt [E][D][H]  (reuse buffer after ffn1)
  transpose_conv_kernel<<<dim3(DDIM / 64, HDIM / 64, NEXP), 256, 0, stream>>>(
      W2, Wt, HDIM, DDIM);
  // ffn2: out[stok[pos]] = Hs[pos] @ W2[e] + b2[e]
  ffn_kernel<HDIM, DDIM, false>
      <<<dim3(DDIM / 128, MAXWL), 256, 0, stream>>>(
          Hs, Wt, b2, counts, offs, wl, stok, nullptr, out);
}

// Round 6
// 469.703 us; speedup vs baseline: 2.7008x; 1.0697x over previous
//
#include <hip/hip_runtime.h>
#include <hip/hip_bf16.h>
#include <stdint.h>

#define NTOK 8192
#define DDIM 1024
#define HDIM 4096
#define NEXP 8
#define MAXWL 48

typedef __attribute__((ext_vector_type(4))) float f32x4;
typedef __attribute__((ext_vector_type(8))) short s16x8;
typedef __attribute__((ext_vector_type(8))) unsigned short u16x8;

__device__ __forceinline__ unsigned short f2bf(float f) {
  union { float f; unsigned int u; } v; v.f = f;
  unsigned int u = v.u;
  u += 0x7FFFu + ((u >> 16) & 1u);   // round-to-nearest-even
  return (unsigned short)(u >> 16);
}

typedef __attribute__((address_space(3))) unsigned char lds_u8;
typedef const __attribute__((address_space(1))) unsigned char glb_u8;

__device__ __forceinline__ void load_lds16(const void* g, void* l) {
  __builtin_amdgcn_global_load_lds((glb_u8*)g, (lds_u8*)l, 16, 0, 0);
}

template <int VM> __device__ __forceinline__ void wait_vm() {
  if constexpr (VM == 8) asm volatile("s_waitcnt vmcnt(8)" ::: "memory");
  else if constexpr (VM == 4) asm volatile("s_waitcnt vmcnt(4)" ::: "memory");
  else asm volatile("s_waitcnt vmcnt(0)" ::: "memory");
}

// ---------------- gate + top-1 routing ----------------
__global__ __launch_bounds__(256) void gate_kernel(
    const float* __restrict__ x, const float* __restrict__ Wg,
    const float* __restrict__ bg, int* __restrict__ counts,
    int* __restrict__ lists) {
  const int lane = threadIdx.x & 63;
  const int tok = blockIdx.x * 4 + (threadIdx.x >> 6);
  const float* xr = x + (size_t)tok * DDIM;
  double acc[NEXP];
#pragma unroll
  for (int e = 0; e < NEXP; ++e) acc[e] = 0.0;
#pragma unroll 4
  for (int it = 0; it < DDIM / 64; ++it) {
    const int d = it * 64 + lane;
    const float xv = xr[d];
    const f32x4 w0 = *(const f32x4*)(Wg + (size_t)d * NEXP);
    const f32x4 w1 = *(const f32x4*)(Wg + (size_t)d * NEXP + 4);
#pragma unroll
    for (int j = 0; j < 4; ++j) {
      acc[j]     += (double)xv * (double)w0[j];
      acc[4 + j] += (double)xv * (double)w1[j];
    }
  }
#pragma unroll
  for (int e = 0; e < NEXP; ++e) {
    double v = acc[e];
#pragma unroll
    for (int off = 32; off > 0; off >>= 1) v += __shfl_xor(v, off, 64);
    acc[e] = v;
  }
  if (lane == 0) {
    int best = 0;
    double bv = acc[0] + (double)bg[0];
#pragma unroll
    for (int e = 1; e < NEXP; ++e) {
      const double v = acc[e] + (double)bg[e];
      if (v > bv) { bv = v; best = e; }   // strict > : first max wins (np argmax)
    }
    const int pos = atomicAdd(&counts[best], 1);
    lists[best * NTOK + pos] = tok;
  }
}

// ---- prefix sum + block work-list (BM=256): wl[i]=(e<<20)|bx, nwl in offs[9] ----
__global__ void offs_kernel(const int* __restrict__ counts, int* __restrict__ offs,
                            int* __restrict__ wl) {
  int s = 0;
#pragma unroll
  for (int e = 0; e < NEXP; ++e) { offs[e] = s; s += counts[e]; }
  offs[NEXP] = s;
  int n = 0;
  for (int e = 0; e < NEXP; ++e) {
    const int nb = (counts[e] + 255) >> 8;
    for (int b = 0; b < nb; ++b) wl[n++] = (e << 20) | b;
  }
  offs[NEXP + 1] = n;
}

// -------- gather tokens into expert-sorted order, convert to bf16 --------
__global__ __launch_bounds__(256) void gather_conv_kernel(
    const float* __restrict__ x, const int* __restrict__ offs,
    const int* __restrict__ lists, int* __restrict__ stok,
    unsigned short* __restrict__ xbs) {
  const int p = blockIdx.x * 4 + (threadIdx.x >> 6);   // sorted position
  const int lane = threadIdx.x & 63;
  int e = 0;
#pragma unroll
  for (int k = 1; k < NEXP; ++k) e += (p >= offs[k]) ? 1 : 0;
  const int tok = lists[e * NTOK + (p - offs[e])];
  if (lane == 0) stok[p] = tok;
  const float* src = x + (size_t)tok * DDIM + lane * 16;
  unsigned short* dst = xbs + (size_t)p * DDIM + lane * 16;
#pragma unroll
  for (int q = 0; q < 2; ++q) {
    const f32x4 a = *(const f32x4*)(src + q * 8);
    const f32x4 b = *(const f32x4*)(src + q * 8 + 4);
    u16x8 o;
#pragma unroll
    for (int j = 0; j < 4; ++j) { o[j] = f2bf(a[j]); o[4 + j] = f2bf(b[j]); }
    *(u16x8*)(dst + q * 8) = o;
  }
}

// -------- transpose + convert: in [E][R][C] fp32 -> out [E][C][R] bf16 --------
__global__ __launch_bounds__(256) void transpose_conv_kernel(
    const float* __restrict__ in, unsigned short* __restrict__ out,
    int R, int C) {
  __shared__ unsigned short T[64][66];
  const int e = blockIdx.z;
  const float* ine = in + (size_t)e * R * C;
  unsigned short* oute = out + (size_t)e * C * R;
  const int c0 = blockIdx.x * 64, r0 = blockIdx.y * 64;
  const int t = threadIdx.x;
  const int tr = t >> 4, tc4 = (t & 15) * 4;
#pragma unroll
  for (int p = 0; p < 4; ++p) {
    const int r = tr + p * 16;
    const f32x4 v = *(const f32x4*)(ine + (size_t)(r0 + r) * C + c0 + tc4);
#pragma unroll
    for (int j = 0; j < 4; ++j) T[r][tc4 + j] = f2bf(v[j]);
  }
  __syncthreads();
#pragma unroll
  for (int p = 0; p < 4; ++p) {
    const int c = tr + p * 16;
    ushort4 o;
    o.x = T[tc4 + 0][c]; o.y = T[tc4 + 1][c];
    o.z = T[tc4 + 2][c]; o.w = T[tc4 + 3][c];
    *(ushort4*)(oute + (size_t)(c0 + c) * R + r0 + tc4) = o;
  }
}

// ---- grouped GEMM: 256x256 tile, BK=32, 8 waves, ring-4 LDS, vmcnt(8) pipeline ----
// A: bf16 [NTOK][K] expert-sorted rows. Bt: bf16 [E][N][K] (K-contiguous rows).
// 1D grid, XCD swizzle (d%8 chunks), wl-fastest within chunk (B-panel L2 reuse).
// Pipeline: stage tile t+3 in phase t; wait vmcnt(8) (tiles t+1,t+2 in flight).
// Bank swizzle: LDS slot s of row r holds global 16B-slot s^(r&3)^((r>>2)&3);
// linear LDS dest (global_load_lds) + pre-swizzled global src + swizzled ds_read.
template <int K, int N, int NCB, bool FUSE1>
__global__ __launch_bounds__(512, 2) void ffn_kernel(
    const unsigned short* __restrict__ A, const unsigned short* __restrict__ Bt,
    const float* __restrict__ bias, const int* __restrict__ counts,
    const int* __restrict__ offs, const int* __restrict__ wl,
    const int* __restrict__ stok, unsigned short* __restrict__ outb,
    float* __restrict__ outf) {
  constexpr int NT = K / 32;
  static_assert((NT & 3) == 0 && NT >= 8, "");
  constexpr int NWG = NCB * MAXWL;
  static_assert((NWG & 7) == 0, "");

  const int d = blockIdx.x;
  const int logical = (d & 7) * (NWG / 8) + (d >> 3);
  const int col0 = (logical / MAXWL) * 256;
  const int wli = logical % MAXWL;
  if (wli >= offs[NEXP + 1]) return;
  const int wle = wl[wli];
  const int e = wle >> 20;
  const int bx = wle & 0xFFFFF;
  const int cnt = counts[e];
  const int row0 = offs[e] + bx * 256;

  // ring-4 buffers, statically named (exact alias analysis; rule from R3)
  __shared__ __align__(16) unsigned short As0[256 * 32], Bs0[256 * 32];
  __shared__ __align__(16) unsigned short As1[256 * 32], Bs1[256 * 32];
  __shared__ __align__(16) unsigned short As2[256 * 32], Bs2[256 * 32];
  __shared__ __align__(16) unsigned short As3[256 * 32], Bs3[256 * 32];

  const int tid = threadIdx.x;
  const int lane = tid & 63;
  const int w = tid >> 6;
  const int wm = w >> 2;          // 2 M-waves
  const int wn = w & 3;           // 4 N-waves
  const int fr = lane & 15;
  const int fj = lane >> 4;

  // staging: thread covers LDS row i*128+(tid>>2), slot tid&3 (16B units);
  // global source slot pre-swizzled by ^(row&3)^((row>>2)&3)
  const int swsrc = (((tid & 3) ^ ((tid >> 2) & 3) ^ ((tid >> 4) & 3))) * 8;
  int gr0 = row0 + (tid >> 2);        if (gr0 > NTOK - 1) gr0 = NTOK - 1;
  int gr1 = row0 + 128 + (tid >> 2);  if (gr1 > NTOK - 1) gr1 = NTOK - 1;
  const unsigned short* srcA0 = A + (size_t)gr0 * K + swsrc;
  const unsigned short* srcA1 = A + (size_t)gr1 * K + swsrc;
  const unsigned short* Bte = Bt + (size_t)e * N * K;
  const unsigned short* srcB0 = Bte + (size_t)(col0 + (tid >> 2)) * K + swsrc;
  const unsigned short* srcB1 = Bte + (size_t)(col0 + 128 + (tid >> 2)) * K + swsrc;

  // ds_read swizzled slot (per-lane constant)
  const int js = ((fj ^ (fr & 3) ^ ((fr >> 2) & 3))) * 8;

  f32x4 acc[8][4];
#pragma unroll
  for (int m = 0; m < 8; ++m)
#pragma unroll
    for (int n = 0; n < 4; ++n) acc[m][n] = f32x4{0.f, 0.f, 0.f, 0.f};

  auto stage = [&](unsigned short* nA, unsigned short* nB, int kel) {
    load_lds16(srcA0 + kel, nA + tid * 8);
    load_lds16(srcA1 + kel, nA + 4096 + tid * 8);
    load_lds16(srcB0 + kel, nB + tid * 8);
    load_lds16(srcB1 + kel, nB + 4096 + tid * 8);
  };

  auto body = [&](const unsigned short* pA, const unsigned short* pB,
                  unsigned short* nA, unsigned short* nB, int knext,
                  bool do_stage) {
    __builtin_amdgcn_s_barrier();
    asm volatile("" ::: "memory");
    if (do_stage) stage(nA, nB, knext);   // issue ASAP; lands >=3 phases later
    s16x8 af[8], bf[4];
#pragma unroll
    for (int m = 0; m < 8; ++m)
      af[m] = *(const s16x8*)(pA + (wm * 128 + m * 16 + fr) * 32 + js);
#pragma unroll
    for (int n = 0; n < 4; ++n)
      bf[n] = *(const s16x8*)(pB + (wn * 64 + n * 16 + fr) * 32 + js);
    __builtin_amdgcn_s_setprio(1);
#pragma unroll
    for (int m = 0; m < 8; ++m)
#pragma unroll
      for (int n = 0; n < 4; ++n)
        acc[m][n] = __builtin_amdgcn_mfma_f32_16x16x32_bf16(af[m], bf[n],
                                                            acc[m][n], 0, 0, 0);
    __builtin_amdgcn_s_setprio(0);
  };

  // prologue: 3 tiles in flight (12 loads/thread outstanding)
  stage(As0, Bs0, 0);
  stage(As1, Bs1, 32);
  stage(As2, Bs2, 64);

#pragma unroll 1
  for (int t = 0; t < NT - 4; t += 4) {
    wait_vm<8>(); body(As0, Bs0, As3, Bs3, (t + 3) * 32, true);
    wait_vm<8>(); body(As1, Bs1, As0, Bs0, (t + 4) * 32, true);
    wait_vm<8>(); body(As2, Bs2, As1, Bs1, (t + 5) * 32, true);
    wait_vm<8>(); body(As3, Bs3, As2, Bs2, (t + 6) * 32, true);
  }
  // tail group: t = NT-4 .. NT-1  (NT % 4 == 0)
  wait_vm<8>(); body(As0, Bs0, As3, Bs3, (NT - 1) * 32, true);
  wait_vm<8>(); body(As1, Bs1, nullptr, nullptr, 0, false);
  wait_vm<4>(); body(As2, Bs2, nullptr, nullptr, 0, false);
  wait_vm<0>(); body(As3, Bs3, nullptr, nullptr, 0, false);

  // epilogue
#pragma unroll
  for (int n = 0; n < 4; ++n) {
    const int col = col0 + wn * 64 + n * 16 + fr;
    const float bv = bias[e * N + col];
#pragma unroll
    for (int m = 0; m < 8; ++m) {
#pragma unroll
      for (int j = 0; j < 4; ++j) {
        const int rl = wm * 128 + m * 16 + fj * 4 + j;
        if (bx * 256 + rl < cnt) {
          if constexpr (FUSE1) {
            outb[(size_t)(row0 + rl) * N + col] = f2bf(fmaxf(acc[m][n][j] + bv, 0.f));
          } else {
            outf[(size_t)stok[row0 + rl] * N + col] = acc[m][n][j] + bv;
          }
        }
      }
    }
  }
}

extern "C" void kernel_launch(void* const* d_in, const int* in_sizes, int n_in,
                              void* d_out, int out_size, void* d_ws, size_t ws_size,
                              hipStream_t stream) {
  (void)in_sizes; (void)n_in; (void)out_size;
  const float* x  = (const float*)d_in[0];
  const float* Wg = (const float*)d_in[1];
  const float* bg = (const float*)d_in[2];
  const float* W1 = (const float*)d_in[3];
  const float* b1 = (const float*)d_in[4];
  const float* W2 = (const float*)d_in[5];
  const float* b2 = (const float*)d_in[6];
  float* out = (float*)d_out;

  char* ws = (char*)d_ws;
  const size_t OFF_CNT = 0;                                    // 8 ints
  const size_t OFF_OFF = 128;                                  // offs[0..9]
  const size_t OFF_WL  = 256;                                  // MAXWL ints
  const size_t OFF_LST = 1024;                                 // E*NTOK ints (256 KB)
  const size_t OFF_STK = OFF_LST + (size_t)NEXP * NTOK * 4;    // NTOK ints
  const size_t OFF_XBS = OFF_STK + (size_t)NTOK * 4;           // NTOK*D bf16 (16 MB)
  const size_t OFF_HS  = OFF_XBS + (size_t)NTOK * DDIM * 2;    // NTOK*H bf16 (64 MB)
  const size_t OFF_WT  = OFF_HS + (size_t)NTOK * HDIM * 2;     // E*D*H bf16 (64 MB)
  const size_t NEED    = OFF_WT + (size_t)NEXP * DDIM * HDIM * 2;
  if (ws_size < NEED) return;

  int* counts = (int*)(ws + OFF_CNT);
  int* offs   = (int*)(ws + OFF_OFF);
  int* wl     = (int*)(ws + OFF_WL);
  int* lists  = (int*)(ws + OFF_LST);
  int* stok   = (int*)(ws + OFF_STK);
  unsigned short* xbs = (unsigned short*)(ws + OFF_XBS);
  unsigned short* Hs  = (unsigned short*)(ws + OFF_HS);
  unsigned short* Wt  = (unsigned short*)(ws + OFF_WT);

  hipMemsetAsync(counts, 0, 128, stream);
  gate_kernel<<<NTOK / 4, 256, 0, stream>>>(x, Wg, bg, counts, lists);
  offs_kernel<<<1, 1, 0, stream>>>(counts, offs, wl);
  gather_conv_kernel<<<NTOK / 4, 256, 0, stream>>>(x, offs, lists, stok, xbs);

  // W1 [E][D][H] -> Wt [E][H][D]
  transpose_conv_kernel<<<dim3(HDIM / 64, DDIM / 64, NEXP), 256, 0, stream>>>(
      W1, Wt, DDIM, HDIM);
  // ffn1: Hs[pos] = relu(xbs[pos] @ W1[e] + b1[e])
  ffn_kernel<DDIM, HDIM, HDIM / 256, true>
      <<<dim3((HDIM / 256) * MAXWL), 512, 0, stream>>>(
          xbs, Wt, b1, counts, offs, wl, stok, Hs, nullptr);
  // W2 [E][H][D] -> Wt [E][D][H]  (reuse buffer after ffn1)
  transpose_conv_kernel<<<dim3(DDIM / 64, HDIM / 64, NEXP), 256, 0, stream>>>(
      W2, Wt, HDIM, DDIM);
  // ffn2: out[stok[pos]] = Hs[pos] @ W2[e] + b2[e]
  ffn_kernel<HDIM, DDIM, DDIM / 256, false>
      <<<dim3((DDIM / 256) * MAXWL), 512, 0, stream>>>(
          Hs, Wt, b2, counts, offs, wl, stok, nullptr, out);
}